// Round 8
// baseline (261.917 us; speedup 1.0000x reference)
//
#include <hip/hip_runtime.h>
#include <hip/hip_bf16.h>

// Interpolate1D: z = interp(cumsum(softmax(x@W + b)), y); outputs (z[B], x[B,64], logdet[B]+log|slope|)
// B=524288, D=64, R=256.
//
// Round-8 = round-6 kernel body (16x16x32 MFMA, 16-row wave tiles — fastest so far)
// with ONE structural change: 1024-thread blocks instead of 256.
//   Occupancy was LDS-capped: 34.8KB/block x 256-thread blocks -> 4 blocks/CU = 16 waves/CU
//   (measured 37%). With 16 waves SHARING one 32KB sW copy: 2 blocks/CU = 32 waves/CU
//   = 8 waves/SIMD. VGPR=64 (measured r6) is exactly the <=64 bound needed for 8 waves/SIMD;
//   __launch_bounds__(1024,8) pins it. TLP replaces the ILP the compiler keeps fusing away
//   (r6/r7 both squeezed to VGPR 64 and serialized ds_read->MFMA->exp chains).
// Also kept from r7: truncating bf16 pack for x (same absmax as RNE, fewer VALU ops).

#define NB 524288
#define NWT (NB / 16)   // 32768 wave-tiles of 16 rows

typedef __attribute__((ext_vector_type(4))) float f32x4;
typedef __attribute__((ext_vector_type(4))) unsigned int u32x4;
typedef __attribute__((ext_vector_type(8))) __bf16 bf16x8;

#define LOG2E 1.4426950408889634f

static __device__ __forceinline__ unsigned short f2b(float f) {
    unsigned u = __builtin_bit_cast(unsigned, f);
    u += 0x7fffu + ((u >> 16) & 1u);          // RNE (W pack only; one-time)
    return (unsigned short)(u >> 16);
}
static __device__ __forceinline__ unsigned pk2t(float a, float b) {
    // truncating bf16x2 pack: hi16(a) | hi16(b)
    return (__builtin_bit_cast(unsigned, a) >> 16) | (__builtin_bit_cast(unsigned, b) & 0xffff0000u);
}

__global__ __launch_bounds__(1024, 8) void interp1d_kernel(
    const float* __restrict__ y, const float* __restrict__ x,
    const float* __restrict__ W, const float* __restrict__ bias,
    const float* __restrict__ logdet, const float* __restrict__ bp,
    float* __restrict__ out)
{
    __shared__ unsigned short sW[2 * 16 * 64 * 8];   // 32KB, [kb][n][lane][i] frag layout
    __shared__ float sBP[256];
    __shared__ float sBias[256];                     // pre-scaled by log2e

    const int t = threadIdx.x;

    // --- once per block: bp, bias*log2e, W*log2e packed into MFMA fragment layout ---
    // 1024 threads: thread handles W column (t&255), k-range [(t>>8)*16, +16)
    if (t < 256) {
        sBP[t]   = bp[t];
        sBias[t] = bias[t] * LOG2E;
    }
    {
        const int col = t & 255;
        const int k0  = (t >> 8) << 4;
        const int lane16lo = col & 15;
        const int n = col >> 4;
        for (int kk = 0; kk < 16; ++kk) {
            int k = k0 + kk;
            float wv = W[k * 256 + col] * LOG2E;      // coalesced within each 256-thread group
            int lane16 = ((k >> 3) & 3) * 16 + lane16lo;
            int kb = k >> 5, i = k & 7;
            sW[((kb * 16 + n) * 64 + lane16) * 8 + i] = f2b(wv);
        }
    }
    __syncthreads();

    const int lane = t & 63;
    const int colb = lane & 15;     // this lane's x-row within the tile (C column)
    const int kH   = lane >> 4;     // 0..3: k-half for frags; C row group (cols kH*4+j)
    const int nw   = gridDim.x << 4;            // 16 waves per block

    int wt = (blockIdx.x << 4) | (t >> 6);

    // --- preload first tile ---
    f32x4 v0 = {}, v1 = {}, v2 = {}, v3 = {};
    float yv = 0.f, ldv = 0.f;
    if (wt < NWT) {
        const float* xr = x + (size_t)((wt << 4) + colb) * 64 + (kH << 3);
        v0 = *reinterpret_cast<const f32x4*>(xr);
        v1 = *reinterpret_cast<const f32x4*>(xr + 4);
        v2 = *reinterpret_cast<const f32x4*>(xr + 32);
        v3 = *reinterpret_cast<const f32x4*>(xr + 36);
        yv  = y[(wt << 4) + colb];
        ldv = logdet[(wt << 4) + colb];
    }

    for (; wt < NWT; wt += nw) {
        const int m0 = wt << 4;
        const int wtn = wt + nw;

        // --- prefetch next tile (latency hidden under this tile's compute) ---
        f32x4 n0 = {}, n1 = {}, n2 = {}, n3 = {};
        float yn = 0.f, ldn = 0.f;
        if (wtn < NWT) {
            const float* xr = x + (size_t)((wtn << 4) + colb) * 64 + (kH << 3);
            n0 = *reinterpret_cast<const f32x4*>(xr);
            n1 = *reinterpret_cast<const f32x4*>(xr + 4);
            n2 = *reinterpret_cast<const f32x4*>(xr + 32);
            n3 = *reinterpret_cast<const f32x4*>(xr + 36);
            yn  = y[(wtn << 4) + colb];
            ldn = logdet[(wtn << 4) + colb];
        }

        // compiler fence: stop LICM from hoisting sW ds_reads out of the tile loop (r3 lesson)
        asm volatile("" ::: "memory");

        // --- passthrough x store from the same registers ---
        float* xo = out + NB + (size_t)(m0 + colb) * 64 + (kH << 3);
        *reinterpret_cast<f32x4*>(xo)      = v0;
        *reinterpret_cast<f32x4*>(xo + 4)  = v1;
        *reinterpret_cast<f32x4*>(xo + 32) = v2;
        *reinterpret_cast<f32x4*>(xo + 36) = v3;

        // --- pack x into B-fragment (col = x-row = lane&15, k = kH*8+i) ---
        u32x4 pa, pb;
        pa[0] = pk2t(v0[0], v0[1]); pa[1] = pk2t(v0[2], v0[3]);
        pa[2] = pk2t(v1[0], v1[1]); pa[3] = pk2t(v1[2], v1[3]);
        pb[0] = pk2t(v2[0], v2[1]); pb[1] = pk2t(v2[2], v2[3]);
        pb[2] = pk2t(v3[0], v3[1]); pb[3] = pk2t(v3[2], v3[3]);
        bf16x8 a0 = __builtin_bit_cast(bf16x8, pa);
        bf16x8 a1 = __builtin_bit_cast(bf16x8, pb);

        // --- phase 1: all 32 MFMAs into acc[16], bias (pre-scaled) as C-init ---
        f32x4 acc[16];
        #pragma unroll
        for (int n = 0; n < 16; ++n) {
            f32x4 c = *reinterpret_cast<const f32x4*>(&sBias[(n << 4) + (kH << 2)]);
            bf16x8 w0 = *reinterpret_cast<const bf16x8*>(&sW[(n * 64 + lane) * 8]);
            bf16x8 w1 = *reinterpret_cast<const bf16x8*>(&sW[((16 + n) * 64 + lane) * 8]);
            c = __builtin_amdgcn_mfma_f32_16x16x32_bf16(w0, a0, c, 0, 0, 0);
            c = __builtin_amdgcn_mfma_f32_16x16x32_bf16(w1, a1, c, 0, 0, 0);
            acc[n] = c;
        }

        // --- searchsorted (branchless: bp ~ linspace so guess is off by <= 1) ---
        int s = (int)floorf(yv * 255.0f);
        s = min(254, max(0, s));
        s += (sBP[s + 1] <= yv) ? 1 : 0;   // bp[255]=1.0 > yv, can't reach 255
        s = min(s, 254);
        s -= (sBP[s] > yv) ? 1 : 0;
        s = max(s, 0);

        // --- per-lane float masks for the partial blocks ---
        const int sb  = s >> 4,  so  = s & 15;            // block/offset of s
        const int sb1 = (s + 1) >> 4, so1 = (s + 1) & 15; // block/offset of s+1
        float m[4], pm[4];
        #pragma unroll
        for (int j = 0; j < 4; ++j) {
            m[j]  = ((kH << 2) + j <= so)  ? 1.f : 0.f;
            pm[j] = ((kH << 2) + j == so1) ? 1.f : 0.f;
        }

        // --- phase 2: exp2 + block sums + select-based prefix assembly ---
        float denom = 0.f, f0s = 0.f, p1 = 0.f;
        #pragma unroll
        for (int n = 0; n < 16; ++n) {
            float e0 = __builtin_amdgcn_exp2f(acc[n][0]);
            float e1 = __builtin_amdgcn_exp2f(acc[n][1]);
            float e2 = __builtin_amdgcn_exp2f(acc[n][2]);
            float e3 = __builtin_amdgcn_exp2f(acc[n][3]);
            float bs = (e0 + e1) + (e2 + e3);
            denom += bs;
            float t0 = fmaf(e3, m[3], fmaf(e2, m[2], fmaf(e1, m[1], e0 * m[0])));
            float tp = fmaf(e3, pm[3], fmaf(e2, pm[2], fmaf(e1, pm[1], e0 * pm[0])));
            f0s += (n < sb) ? bs : ((n == sb) ? t0 : 0.f);
            p1  += (n == sb1) ? tp : 0.f;
        }

        // --- reduce over the 4 kH lanes sharing this x-row ---
        denom += __shfl_xor(denom, 16, 64);
        f0s   += __shfl_xor(f0s,   16, 64);
        p1    += __shfl_xor(p1,    16, 64);
        denom += __shfl_xor(denom, 32, 64);
        f0s   += __shfl_xor(f0s,   32, 64);
        p1    += __shfl_xor(p1,    32, 64);

        if (kH == 0) {   // lanes 0..15 store rows m0..m0+15: contiguous 64B
            float x0 = sBP[s], x1 = sBP[s + 1];
            float inv = 1.0f / denom;
            float f0 = f0s * inv;
            float slope = (p1 * inv) / (x1 - x0);
            out[m0 + colb] = fmaf(slope, yv - x0, f0);
            out[(size_t)NB * 65 + m0 + colb] = ldv + __logf(fabsf(slope));
        }

        // --- rotate prefetched tile in ---
        if (wtn < NWT) {
            v0 = n0; v1 = n1; v2 = n2; v3 = n3;
            yv = yn; ldv = ldn;
        }
    }
}

extern "C" void kernel_launch(void* const* d_in, const int* in_sizes, int n_in,
                              void* d_out, int out_size, void* d_ws, size_t ws_size,
                              hipStream_t stream) {
    (void)in_sizes; (void)n_in; (void)out_size; (void)d_ws; (void)ws_size;
    const float* y      = (const float*)d_in[0];
    const float* x      = (const float*)d_in[1];
    const float* W      = (const float*)d_in[2];
    const float* b      = (const float*)d_in[3];
    const float* logdet = (const float*)d_in[4];
    const float* bp     = (const float*)d_in[5];
    float* out = (float*)d_out;
    // 1024-thread blocks: 16 waves share one 32KB sW copy -> 2 blocks/CU = 32 waves/CU
    // (8 waves/SIMD, needs VGPR<=64 which r6 measured). 512 blocks = all resident, 4 tiles/wave.
    interp1d_kernel<<<dim3(512), dim3(1024), 0, stream>>>(y, x, W, b, logdet, bp, out);
}

// Round 9
// 175.151 us; speedup vs baseline: 1.4954x; 1.4954x over previous
//
#include <hip/hip_runtime.h>
#include <hip/hip_bf16.h>

// Interpolate1D: z = interp(cumsum(softmax(x@W + b)), y); outputs (z[B], x[B,64], logdet[B]+log|slope|)
// B=524288, D=64, R=256.
//
// Round-9: occupancy unlock without the r8 spill.
//   Register model (r8 lesson): unified VGPR/AGPR file -> any structure with a live
//   64-f32 accumulator is pinned at 4 waves/SIMD; demanding 8 spills acc to scratch
//   (r8: VGPR=32, 1.04GB traffic). Only the FUSED body (acc transient per n-block,
//   r4 measured 64 regs total) can hit the <=64 budget that 8 waves/SIMD needs.
//   LDS model: sW=32KB capped blocks at 4/CU. Fix: pre-pack W into d_ws (global,
//   frag layout, bf16, x log2e) with a tiny pack kernel; main kernel loads W-frags
//   from global (32KB -> L2-resident on every XCD). LDS drops to 2KB -> 8 blocks/CU.
//   No software prefetch: saves ~16 regs; 8-wave TLP hides x-load latency instead.
// Kept (all verified passing): swapped MFMA operands (W as A), 16x16x32 bf16 shape,
// log2e pre-scale + __builtin_amdgcn_exp2f, float-mask prefix sums, branchless
// searchsorted, truncating bf16 x-pack, LICM fence.
// Assumes ws_size >= 33KB (wpack 32KB + bpack 1KB).

#define NB 524288
#define NWT (NB / 16)   // 32768 wave-tiles of 16 rows

typedef __attribute__((ext_vector_type(4))) float f32x4;
typedef __attribute__((ext_vector_type(4))) unsigned int u32x4;
typedef __attribute__((ext_vector_type(8))) __bf16 bf16x8;

#define LOG2E 1.4426950408889634f

static __device__ __forceinline__ unsigned short f2b(float f) {
    unsigned u = __builtin_bit_cast(unsigned, f);
    u += 0x7fffu + ((u >> 16) & 1u);          // RNE (W pack only; one-time)
    return (unsigned short)(u >> 16);
}
static __device__ __forceinline__ unsigned pk2t(float a, float b) {
    // truncating bf16x2 pack: hi16(a) | hi16(b)
    return (__builtin_bit_cast(unsigned, a) >> 16) | (__builtin_bit_cast(unsigned, b) & 0xffff0000u);
}

// --- pack kernel: W*log2e -> bf16 MFMA-frag layout in d_ws; bias*log2e -> d_ws tail ---
__global__ __launch_bounds__(256) void pack_kernel(
    const float* __restrict__ W, const float* __restrict__ bias,
    unsigned short* __restrict__ wpack, float* __restrict__ bpack)
{
    const int k = blockIdx.x;       // 64 blocks: one W row each
    const int t = threadIdx.x;      // W column
    float wv = W[k * 256 + t] * LOG2E;
    int lane16 = ((k >> 3) & 3) * 16 + (t & 15);
    int n = t >> 4, kb = k >> 5, i = k & 7;
    wpack[((kb * 16 + n) * 64 + lane16) * 8 + i] = f2b(wv);
    if (k == 0) bpack[t] = bias[t] * LOG2E;
}

__global__ __launch_bounds__(256, 8) void interp1d_kernel(
    const float* __restrict__ y, const float* __restrict__ x,
    const unsigned short* __restrict__ wpack, const float* __restrict__ bpack,
    const float* __restrict__ logdet, const float* __restrict__ bp,
    float* __restrict__ out)
{
    __shared__ float sBP[256];
    __shared__ float sBias[256];    // 2KB total LDS -> 8 blocks/CU

    const int t = threadIdx.x;
    sBP[t]   = bp[t];
    sBias[t] = bpack[t];
    __syncthreads();

    const int lane = t & 63;
    const int colb = lane & 15;     // this lane's x-row within the tile (C column)
    const int kH   = lane >> 4;     // 0..3: k-half for frags; C row group (cols kH*4+j)
    const int nw   = gridDim.x << 2;

    for (int wt = (blockIdx.x << 2) | (t >> 6); wt < NWT; wt += nw) {
        const int m0 = wt << 4;

        // --- load this wave's 16 x-rows + y + logdet (no prefetch: 8-wave TLP hides it) ---
        const float* xr = x + (size_t)(m0 + colb) * 64 + (kH << 3);
        f32x4 v0 = *reinterpret_cast<const f32x4*>(xr);
        f32x4 v1 = *reinterpret_cast<const f32x4*>(xr + 4);
        f32x4 v2 = *reinterpret_cast<const f32x4*>(xr + 32);
        f32x4 v3 = *reinterpret_cast<const f32x4*>(xr + 36);
        float yv  = y[m0 + colb];
        float ldv = logdet[m0 + colb];

        // fence: keep the wpack global loads inside the tile loop (r3 LICM lesson)
        asm volatile("" ::: "memory");

        // --- passthrough x store from the same registers ---
        float* xo = out + NB + (size_t)(m0 + colb) * 64 + (kH << 3);
        *reinterpret_cast<f32x4*>(xo)      = v0;
        *reinterpret_cast<f32x4*>(xo + 4)  = v1;
        *reinterpret_cast<f32x4*>(xo + 32) = v2;
        *reinterpret_cast<f32x4*>(xo + 36) = v3;

        // --- pack x into B-fragment (col = x-row = lane&15, k = kH*8+i) ---
        u32x4 pa, pb;
        pa[0] = pk2t(v0[0], v0[1]); pa[1] = pk2t(v0[2], v0[3]);
        pa[2] = pk2t(v1[0], v1[1]); pa[3] = pk2t(v1[2], v1[3]);
        pb[0] = pk2t(v2[0], v2[1]); pb[1] = pk2t(v2[2], v2[3]);
        pb[2] = pk2t(v3[0], v3[1]); pb[3] = pk2t(v3[2], v3[3]);
        bf16x8 a0 = __builtin_bit_cast(bf16x8, pa);
        bf16x8 a1 = __builtin_bit_cast(bf16x8, pb);

        // --- searchsorted (branchless: bp ~ linspace so guess is off by <= 1) ---
        int s = (int)floorf(yv * 255.0f);
        s = min(254, max(0, s));
        s += (sBP[s + 1] <= yv) ? 1 : 0;   // bp[255]=1.0 > yv, can't reach 255
        s = min(s, 254);
        s -= (sBP[s] > yv) ? 1 : 0;
        s = max(s, 0);

        // --- per-lane float masks for the partial blocks ---
        const int sb  = s >> 4,  so  = s & 15;            // block/offset of s
        const int sb1 = (s + 1) >> 4, so1 = (s + 1) & 15; // block/offset of s+1
        float m[4], pm[4];
        #pragma unroll
        for (int j = 0; j < 4; ++j) {
            m[j]  = ((kH << 2) + j <= so)  ? 1.f : 0.f;
            pm[j] = ((kH << 2) + j == so1) ? 1.f : 0.f;
        }

        // --- fused n-loop: W-frags from global (L2-resident), MFMA, exp2, masked sums ---
        float denom = 0.f, f0s = 0.f, p1 = 0.f;
        #pragma unroll
        for (int n = 0; n < 16; ++n) {
            bf16x8 w0 = *reinterpret_cast<const bf16x8*>(wpack + (n * 64 + lane) * 8);
            bf16x8 w1 = *reinterpret_cast<const bf16x8*>(wpack + ((16 + n) * 64 + lane) * 8);
            f32x4 c = *reinterpret_cast<const f32x4*>(&sBias[(n << 4) + (kH << 2)]);
            c = __builtin_amdgcn_mfma_f32_16x16x32_bf16(w0, a0, c, 0, 0, 0);
            c = __builtin_amdgcn_mfma_f32_16x16x32_bf16(w1, a1, c, 0, 0, 0);
            float e0 = __builtin_amdgcn_exp2f(c[0]);
            float e1 = __builtin_amdgcn_exp2f(c[1]);
            float e2 = __builtin_amdgcn_exp2f(c[2]);
            float e3 = __builtin_amdgcn_exp2f(c[3]);
            float bs = (e0 + e1) + (e2 + e3);
            denom += bs;
            float t0 = fmaf(e3, m[3], fmaf(e2, m[2], fmaf(e1, m[1], e0 * m[0])));
            float tp = fmaf(e3, pm[3], fmaf(e2, pm[2], fmaf(e1, pm[1], e0 * pm[0])));
            f0s += (n < sb) ? bs : ((n == sb) ? t0 : 0.f);
            p1  += (n == sb1) ? tp : 0.f;
        }

        // --- reduce over the 4 kH lanes sharing this x-row ---
        denom += __shfl_xor(denom, 16, 64);
        f0s   += __shfl_xor(f0s,   16, 64);
        p1    += __shfl_xor(p1,    16, 64);
        denom += __shfl_xor(denom, 32, 64);
        f0s   += __shfl_xor(f0s,   32, 64);
        p1    += __shfl_xor(p1,    32, 64);

        if (kH == 0) {   // lanes 0..15 store rows m0..m0+15: contiguous 64B
            float x0 = sBP[s], x1 = sBP[s + 1];
            float inv = 1.0f / denom;
            float f0 = f0s * inv;
            float slope = (p1 * inv) / (x1 - x0);
            out[m0 + colb] = fmaf(slope, yv - x0, f0);
            out[(size_t)NB * 65 + m0 + colb] = ldv + __logf(fabsf(slope));
        }
    }
}

extern "C" void kernel_launch(void* const* d_in, const int* in_sizes, int n_in,
                              void* d_out, int out_size, void* d_ws, size_t ws_size,
                              hipStream_t stream) {
    (void)in_sizes; (void)n_in; (void)out_size; (void)ws_size;
    const float* y      = (const float*)d_in[0];
    const float* x      = (const float*)d_in[1];
    const float* W      = (const float*)d_in[2];
    const float* b      = (const float*)d_in[3];
    const float* logdet = (const float*)d_in[4];
    const float* bp     = (const float*)d_in[5];
    float* out = (float*)d_out;

    unsigned short* wpack = (unsigned short*)d_ws;            // 32KB frag-layout bf16 W
    float* bpack = (float*)((char*)d_ws + 32768);             // 1KB bias*log2e

    pack_kernel<<<dim3(64), dim3(256), 0, stream>>>(W, b, wpack, bpack);
    // 2048 blocks = 8 blocks/CU (2KB LDS, <=64 regs) -> 32 waves/CU; 4 tiles/wave.
    interp1d_kernel<<<dim3(2048), dim3(256), 0, stream>>>(y, x, wpack, bpack, logdet, bp, out);
}

// Round 10
// 67.488 us; speedup vs baseline: 3.8809x; 2.5953x over previous
//
#include <hip/hip_runtime.h>
#include <hip/hip_bf16.h>

// Interpolate1D: z = interp(cumsum(softmax(x@W + b)), y); outputs (z[B], x[B,64], logdet[B]+log|slope|)
// B=524288, D=64, R=256.
//
// Round-10 = round-6 body (best: 72us, VGPR=64 natural) with 512-THREAD BLOCKS:
//   8 waves share one 32KB sW copy. LDS cap: floor(160/34.8)=4 blocks/CU x 8 waves
//   = 32 waves/CU = 8 waves/SIMD — double r6's 16 waves/CU, same per-wave code.
//   launch_bounds(512,4) keeps the SAME 128-reg budget as r6 (which landed on 64
//   naturally). r8/r9 lesson: never DEMAND 8 waves/EU (allocator squeezes to 32
//   regs and spills: 0.5-1GB scratch traffic). Raise waves/BLOCK instead.
// Kept identical from r6: 16x16x32 MFMA swapped operands, register prefetch, LICM
// fence, log2e pre-scale + __builtin_amdgcn_exp2f, float-mask prefix sums,
// branchless searchsorted, truncating bf16 x-pack.

#define NB 524288
#define NWT (NB / 16)   // 32768 wave-tiles of 16 rows

typedef __attribute__((ext_vector_type(4))) float f32x4;
typedef __attribute__((ext_vector_type(4))) unsigned int u32x4;
typedef __attribute__((ext_vector_type(8))) __bf16 bf16x8;

#define LOG2E 1.4426950408889634f

static __device__ __forceinline__ unsigned short f2b(float f) {
    unsigned u = __builtin_bit_cast(unsigned, f);
    u += 0x7fffu + ((u >> 16) & 1u);          // RNE (W pack only; one-time)
    return (unsigned short)(u >> 16);
}
static __device__ __forceinline__ unsigned pk2t(float a, float b) {
    // truncating bf16x2 pack: hi16(a) | hi16(b)
    return (__builtin_bit_cast(unsigned, a) >> 16) | (__builtin_bit_cast(unsigned, b) & 0xffff0000u);
}

__global__ __launch_bounds__(512, 4) void interp1d_kernel(
    const float* __restrict__ y, const float* __restrict__ x,
    const float* __restrict__ W, const float* __restrict__ bias,
    const float* __restrict__ logdet, const float* __restrict__ bp,
    float* __restrict__ out)
{
    __shared__ unsigned short sW[2 * 16 * 64 * 8];   // 32KB, [kb][n][lane][i] frag layout
    __shared__ float sBP[256];
    __shared__ float sBias[256];                     // pre-scaled by log2e

    const int t = threadIdx.x;

    // --- once per block: bp, bias*log2e, W*log2e packed into MFMA fragment layout ---
    // 512 threads: thread handles W column (t&255), k-range [(t>>8)*32, +32)
    if (t < 256) {
        sBP[t]   = bp[t];
        sBias[t] = bias[t] * LOG2E;
    }
    {
        const int col = t & 255;
        const int k0  = (t >> 8) << 5;
        const int lane16lo = col & 15;
        const int n = col >> 4;
        for (int kk = 0; kk < 32; ++kk) {
            int k = k0 + kk;
            float wv = W[k * 256 + col] * LOG2E;      // coalesced within each 256-thread half
            int lane16 = ((k >> 3) & 3) * 16 + lane16lo;
            int kb = k >> 5, i = k & 7;
            sW[((kb * 16 + n) * 64 + lane16) * 8 + i] = f2b(wv);
        }
    }
    __syncthreads();

    const int lane = t & 63;
    const int colb = lane & 15;     // this lane's x-row within the tile (C column)
    const int kH   = lane >> 4;     // 0..3: k-half for frags; C row group (cols kH*4+j)
    const int nw   = gridDim.x << 3;            // 8 waves per block

    int wt = (blockIdx.x << 3) | (t >> 6);

    // --- preload first tile ---
    f32x4 v0 = {}, v1 = {}, v2 = {}, v3 = {};
    float yv = 0.f, ldv = 0.f;
    if (wt < NWT) {
        const float* xr = x + (size_t)((wt << 4) + colb) * 64 + (kH << 3);
        v0 = *reinterpret_cast<const f32x4*>(xr);
        v1 = *reinterpret_cast<const f32x4*>(xr + 4);
        v2 = *reinterpret_cast<const f32x4*>(xr + 32);
        v3 = *reinterpret_cast<const f32x4*>(xr + 36);
        yv  = y[(wt << 4) + colb];
        ldv = logdet[(wt << 4) + colb];
    }

    for (; wt < NWT; wt += nw) {
        const int m0 = wt << 4;
        const int wtn = wt + nw;

        // --- prefetch next tile (latency hidden under this tile's compute) ---
        f32x4 n0 = {}, n1 = {}, n2 = {}, n3 = {};
        float yn = 0.f, ldn = 0.f;
        if (wtn < NWT) {
            const float* xr = x + (size_t)((wtn << 4) + colb) * 64 + (kH << 3);
            n0 = *reinterpret_cast<const f32x4*>(xr);
            n1 = *reinterpret_cast<const f32x4*>(xr + 4);
            n2 = *reinterpret_cast<const f32x4*>(xr + 32);
            n3 = *reinterpret_cast<const f32x4*>(xr + 36);
            yn  = y[(wtn << 4) + colb];
            ldn = logdet[(wtn << 4) + colb];
        }

        // compiler fence: stop LICM from hoisting sW ds_reads out of the tile loop (r3 lesson)
        asm volatile("" ::: "memory");

        // --- passthrough x store from the same registers ---
        float* xo = out + NB + (size_t)(m0 + colb) * 64 + (kH << 3);
        *reinterpret_cast<f32x4*>(xo)      = v0;
        *reinterpret_cast<f32x4*>(xo + 4)  = v1;
        *reinterpret_cast<f32x4*>(xo + 32) = v2;
        *reinterpret_cast<f32x4*>(xo + 36) = v3;

        // --- pack x into B-fragment (col = x-row = lane&15, k = kH*8+i) ---
        u32x4 pa, pb;
        pa[0] = pk2t(v0[0], v0[1]); pa[1] = pk2t(v0[2], v0[3]);
        pa[2] = pk2t(v1[0], v1[1]); pa[3] = pk2t(v1[2], v1[3]);
        pb[0] = pk2t(v2[0], v2[1]); pb[1] = pk2t(v2[2], v2[3]);
        pb[2] = pk2t(v3[0], v3[1]); pb[3] = pk2t(v3[2], v3[3]);
        bf16x8 a0 = __builtin_bit_cast(bf16x8, pa);
        bf16x8 a1 = __builtin_bit_cast(bf16x8, pb);

        // --- phase 1: all 32 MFMAs into acc[16], bias (pre-scaled) as C-init ---
        f32x4 acc[16];
        #pragma unroll
        for (int n = 0; n < 16; ++n) {
            f32x4 c = *reinterpret_cast<const f32x4*>(&sBias[(n << 4) + (kH << 2)]);
            bf16x8 w0 = *reinterpret_cast<const bf16x8*>(&sW[(n * 64 + lane) * 8]);
            bf16x8 w1 = *reinterpret_cast<const bf16x8*>(&sW[((16 + n) * 64 + lane) * 8]);
            c = __builtin_amdgcn_mfma_f32_16x16x32_bf16(w0, a0, c, 0, 0, 0);
            c = __builtin_amdgcn_mfma_f32_16x16x32_bf16(w1, a1, c, 0, 0, 0);
            acc[n] = c;
        }

        // --- searchsorted (branchless: bp ~ linspace so guess is off by <= 1) ---
        int s = (int)floorf(yv * 255.0f);
        s = min(254, max(0, s));
        s += (sBP[s + 1] <= yv) ? 1 : 0;   // bp[255]=1.0 > yv, can't reach 255
        s = min(s, 254);
        s -= (sBP[s] > yv) ? 1 : 0;
        s = max(s, 0);

        // --- per-lane float masks for the partial blocks ---
        const int sb  = s >> 4,  so  = s & 15;            // block/offset of s
        const int sb1 = (s + 1) >> 4, so1 = (s + 1) & 15; // block/offset of s+1
        float m[4], pm[4];
        #pragma unroll
        for (int j = 0; j < 4; ++j) {
            m[j]  = ((kH << 2) + j <= so)  ? 1.f : 0.f;
            pm[j] = ((kH << 2) + j == so1) ? 1.f : 0.f;
        }

        // --- phase 2: exp2 + block sums + select-based prefix assembly ---
        float denom = 0.f, f0s = 0.f, p1 = 0.f;
        #pragma unroll
        for (int n = 0; n < 16; ++n) {
            float e0 = __builtin_amdgcn_exp2f(acc[n][0]);
            float e1 = __builtin_amdgcn_exp2f(acc[n][1]);
            float e2 = __builtin_amdgcn_exp2f(acc[n][2]);
            float e3 = __builtin_amdgcn_exp2f(acc[n][3]);
            float bs = (e0 + e1) + (e2 + e3);
            denom += bs;
            float t0 = fmaf(e3, m[3], fmaf(e2, m[2], fmaf(e1, m[1], e0 * m[0])));
            float tp = fmaf(e3, pm[3], fmaf(e2, pm[2], fmaf(e1, pm[1], e0 * pm[0])));
            f0s += (n < sb) ? bs : ((n == sb) ? t0 : 0.f);
            p1  += (n == sb1) ? tp : 0.f;
        }

        // --- reduce over the 4 kH lanes sharing this x-row ---
        denom += __shfl_xor(denom, 16, 64);
        f0s   += __shfl_xor(f0s,   16, 64);
        p1    += __shfl_xor(p1,    16, 64);
        denom += __shfl_xor(denom, 32, 64);
        f0s   += __shfl_xor(f0s,   32, 64);
        p1    += __shfl_xor(p1,    32, 64);

        if (kH == 0) {   // lanes 0..15 store rows m0..m0+15: contiguous 64B
            float x0 = sBP[s], x1 = sBP[s + 1];
            float inv = 1.0f / denom;
            float f0 = f0s * inv;
            float slope = (p1 * inv) / (x1 - x0);
            out[m0 + colb] = fmaf(slope, yv - x0, f0);
            out[(size_t)NB * 65 + m0 + colb] = ldv + __logf(fabsf(slope));
        }

        // --- rotate prefetched tile in ---
        if (wtn < NWT) {
            v0 = n0; v1 = n1; v2 = n2; v3 = n3;
            yv = yn; ldv = ldn;
        }
    }
}

extern "C" void kernel_launch(void* const* d_in, const int* in_sizes, int n_in,
                              void* d_out, int out_size, void* d_ws, size_t ws_size,
                              hipStream_t stream) {
    (void)in_sizes; (void)n_in; (void)out_size; (void)d_ws; (void)ws_size;
    const float* y      = (const float*)d_in[0];
    const float* x      = (const float*)d_in[1];
    const float* W      = (const float*)d_in[2];
    const float* b      = (const float*)d_in[3];
    const float* logdet = (const float*)d_in[4];
    const float* bp     = (const float*)d_in[5];
    float* out = (float*)d_out;
    // 512-thread blocks: 8 waves share one 32KB sW -> LDS caps at 4 blocks/CU
    // = 32 waves/CU (8/SIMD) if VGPR stays at the natural 64. 1024 blocks = 4/CU
    // exactly resident; 4 tiles/wave.
    interp1d_kernel<<<dim3(1024), dim3(512), 0, stream>>>(y, x, W, b, logdet, bp, out);
}

// Round 11
// 64.175 us; speedup vs baseline: 4.0813x; 1.0516x over previous
//
#include <hip/hip_runtime.h>
#include <hip/hip_bf16.h>

// Interpolate1D: z = interp(cumsum(softmax(x@W + b)), y); outputs (z[B], x[B,64], logdet[B]+log|slope|)
// B=524288, D=64, R=256.
//
// Round-11 = the two proven-independent occupancy fixes combined:
//  - FUSED n-loop (transient MFMA accumulator): r4 measured 64 regs TOTAL incl. prefetch.
//    r10's phase-split acc[16] lives in AGPRs -> unified-file footprint ~128/wave ->
//    pinned at 4 waves/SIMD no matter what (the real reason occupancy stalled at 36%).
//  - 512-thread blocks: 8 waves share one 32KB sW (r10 win), LDS cap 4 blocks/CU
//    = 32 waves/CU = 8 waves/SIMD when regs <= 64.
//  Never DEMAND 8 waves/EU (r8/r9: allocator splits 32 VGPR + 32 AGPR and spills);
//  (512,4) keeps budget 128 and lets natural usage (<=64) unlock 8 waves/SIMD.
// Kept: 16x16x32 MFMA swapped operands (W as A), register prefetch, LICM fence,
// log2e pre-scale + __builtin_amdgcn_exp2f, float-mask prefix sums, branchless
// searchsorted, truncating bf16 x-pack.

#define NB 524288
#define NWT (NB / 16)   // 32768 wave-tiles of 16 rows

typedef __attribute__((ext_vector_type(4))) float f32x4;
typedef __attribute__((ext_vector_type(4))) unsigned int u32x4;
typedef __attribute__((ext_vector_type(8))) __bf16 bf16x8;

#define LOG2E 1.4426950408889634f

static __device__ __forceinline__ unsigned short f2b(float f) {
    unsigned u = __builtin_bit_cast(unsigned, f);
    u += 0x7fffu + ((u >> 16) & 1u);          // RNE (W pack only; one-time)
    return (unsigned short)(u >> 16);
}
static __device__ __forceinline__ unsigned pk2t(float a, float b) {
    // truncating bf16x2 pack: hi16(a) | hi16(b)
    return (__builtin_bit_cast(unsigned, a) >> 16) | (__builtin_bit_cast(unsigned, b) & 0xffff0000u);
}

__global__ __launch_bounds__(512, 4) void interp1d_kernel(
    const float* __restrict__ y, const float* __restrict__ x,
    const float* __restrict__ W, const float* __restrict__ bias,
    const float* __restrict__ logdet, const float* __restrict__ bp,
    float* __restrict__ out)
{
    __shared__ unsigned short sW[2 * 16 * 64 * 8];   // 32KB, [kb][n][lane][i] frag layout
    __shared__ float sBP[256];
    __shared__ float sBias[256];                     // pre-scaled by log2e

    const int t = threadIdx.x;

    // --- once per block: bp, bias*log2e, W*log2e packed into MFMA fragment layout ---
    // 512 threads: thread handles W column (t&255), k-range [(t>>8)*32, +32)
    if (t < 256) {
        sBP[t]   = bp[t];
        sBias[t] = bias[t] * LOG2E;
    }
    {
        const int col = t & 255;
        const int k0  = (t >> 8) << 5;
        const int lane16lo = col & 15;
        const int n = col >> 4;
        for (int kk = 0; kk < 32; ++kk) {
            int k = k0 + kk;
            float wv = W[k * 256 + col] * LOG2E;      // coalesced within each 256-thread half
            int lane16 = ((k >> 3) & 3) * 16 + lane16lo;
            int kb = k >> 5, i = k & 7;
            sW[((kb * 16 + n) * 64 + lane16) * 8 + i] = f2b(wv);
        }
    }
    __syncthreads();

    const int lane = t & 63;
    const int colb = lane & 15;     // this lane's x-row within the tile (C column)
    const int kH   = lane >> 4;     // 0..3: k-half for frags; C row group (cols kH*4+j)
    const int nw   = gridDim.x << 3;            // 8 waves per block

    int wt = (blockIdx.x << 3) | (t >> 6);

    // --- preload first tile ---
    f32x4 v0 = {}, v1 = {}, v2 = {}, v3 = {};
    float yv = 0.f, ldv = 0.f;
    if (wt < NWT) {
        const float* xr = x + (size_t)((wt << 4) + colb) * 64 + (kH << 3);
        v0 = *reinterpret_cast<const f32x4*>(xr);
        v1 = *reinterpret_cast<const f32x4*>(xr + 4);
        v2 = *reinterpret_cast<const f32x4*>(xr + 32);
        v3 = *reinterpret_cast<const f32x4*>(xr + 36);
        yv  = y[(wt << 4) + colb];
        ldv = logdet[(wt << 4) + colb];
    }

    for (; wt < NWT; wt += nw) {
        const int m0 = wt << 4;
        const int wtn = wt + nw;

        // --- prefetch next tile (latency hidden under this tile's compute) ---
        f32x4 n0 = {}, n1 = {}, n2 = {}, n3 = {};
        float yn = 0.f, ldn = 0.f;
        if (wtn < NWT) {
            const float* xr = x + (size_t)((wtn << 4) + colb) * 64 + (kH << 3);
            n0 = *reinterpret_cast<const f32x4*>(xr);
            n1 = *reinterpret_cast<const f32x4*>(xr + 4);
            n2 = *reinterpret_cast<const f32x4*>(xr + 32);
            n3 = *reinterpret_cast<const f32x4*>(xr + 36);
            yn  = y[(wtn << 4) + colb];
            ldn = logdet[(wtn << 4) + colb];
        }

        // compiler fence: stop LICM from hoisting sW ds_reads out of the tile loop (r3 lesson)
        asm volatile("" ::: "memory");

        // --- passthrough x store from the same registers ---
        float* xo = out + NB + (size_t)(m0 + colb) * 64 + (kH << 3);
        *reinterpret_cast<f32x4*>(xo)      = v0;
        *reinterpret_cast<f32x4*>(xo + 4)  = v1;
        *reinterpret_cast<f32x4*>(xo + 32) = v2;
        *reinterpret_cast<f32x4*>(xo + 36) = v3;

        // --- pack x into B-fragment (col = x-row = lane&15, k = kH*8+i) ---
        u32x4 pa, pb;
        pa[0] = pk2t(v0[0], v0[1]); pa[1] = pk2t(v0[2], v0[3]);
        pa[2] = pk2t(v1[0], v1[1]); pa[3] = pk2t(v1[2], v1[3]);
        pb[0] = pk2t(v2[0], v2[1]); pb[1] = pk2t(v2[2], v2[3]);
        pb[2] = pk2t(v3[0], v3[1]); pb[3] = pk2t(v3[2], v3[3]);
        bf16x8 a0 = __builtin_bit_cast(bf16x8, pa);
        bf16x8 a1 = __builtin_bit_cast(bf16x8, pb);

        // --- searchsorted (branchless: bp ~ linspace so guess is off by <= 1) ---
        int s = (int)floorf(yv * 255.0f);
        s = min(254, max(0, s));
        s += (sBP[s + 1] <= yv) ? 1 : 0;   // bp[255]=1.0 > yv, can't reach 255
        s = min(s, 254);
        s -= (sBP[s] > yv) ? 1 : 0;
        s = max(s, 0);

        // --- per-lane float masks for the partial blocks ---
        const int sb  = s >> 4,  so  = s & 15;            // block/offset of s
        const int sb1 = (s + 1) >> 4, so1 = (s + 1) & 15; // block/offset of s+1
        float m[4], pm[4];
        #pragma unroll
        for (int j = 0; j < 4; ++j) {
            m[j]  = ((kH << 2) + j <= so)  ? 1.f : 0.f;
            pm[j] = ((kH << 2) + j == so1) ? 1.f : 0.f;
        }

        // --- FUSED n-loop: MFMA (transient c) -> exp2 -> masked sums. No persistent
        //     accumulator array => no AGPR footprint => 8 waves/SIMD possible. ---
        float denom = 0.f, f0s = 0.f, p1 = 0.f;
        #pragma unroll
        for (int n = 0; n < 16; ++n) {
            bf16x8 w0 = *reinterpret_cast<const bf16x8*>(&sW[(n * 64 + lane) * 8]);
            bf16x8 w1 = *reinterpret_cast<const bf16x8*>(&sW[((16 + n) * 64 + lane) * 8]);
            f32x4 c = *reinterpret_cast<const f32x4*>(&sBias[(n << 4) + (kH << 2)]);
            c = __builtin_amdgcn_mfma_f32_16x16x32_bf16(w0, a0, c, 0, 0, 0);
            c = __builtin_amdgcn_mfma_f32_16x16x32_bf16(w1, a1, c, 0, 0, 0);
            float e0 = __builtin_amdgcn_exp2f(c[0]);
            float e1 = __builtin_amdgcn_exp2f(c[1]);
            float e2 = __builtin_amdgcn_exp2f(c[2]);
            float e3 = __builtin_amdgcn_exp2f(c[3]);
            float bs = (e0 + e1) + (e2 + e3);
            denom += bs;
            float t0 = fmaf(e3, m[3], fmaf(e2, m[2], fmaf(e1, m[1], e0 * m[0])));
            float tp = fmaf(e3, pm[3], fmaf(e2, pm[2], fmaf(e1, pm[1], e0 * pm[0])));
            f0s += (n < sb) ? bs : ((n == sb) ? t0 : 0.f);
            p1  += (n == sb1) ? tp : 0.f;
        }

        // --- reduce over the 4 kH lanes sharing this x-row ---
        denom += __shfl_xor(denom, 16, 64);
        f0s   += __shfl_xor(f0s,   16, 64);
        p1    += __shfl_xor(p1,    16, 64);
        denom += __shfl_xor(denom, 32, 64);
        f0s   += __shfl_xor(f0s,   32, 64);
        p1    += __shfl_xor(p1,    32, 64);

        if (kH == 0) {   // lanes 0..15 store rows m0..m0+15: contiguous 64B
            float x0 = sBP[s], x1 = sBP[s + 1];
            float inv = 1.0f / denom;
            float f0 = f0s * inv;
            float slope = (p1 * inv) / (x1 - x0);
            out[m0 + colb] = fmaf(slope, yv - x0, f0);
            out[(size_t)NB * 65 + m0 + colb] = ldv + __logf(fabsf(slope));
        }

        // --- rotate prefetched tile in ---
        if (wtn < NWT) {
            v0 = n0; v1 = n1; v2 = n2; v3 = n3;
            yv = yn; ldv = ldn;
        }
    }
}

extern "C" void kernel_launch(void* const* d_in, const int* in_sizes, int n_in,
                              void* d_out, int out_size, void* d_ws, size_t ws_size,
                              hipStream_t stream) {
    (void)in_sizes; (void)n_in; (void)out_size; (void)d_ws; (void)ws_size;
    const float* y      = (const float*)d_in[0];
    const float* x      = (const float*)d_in[1];
    const float* W      = (const float*)d_in[2];
    const float* b      = (const float*)d_in[3];
    const float* logdet = (const float*)d_in[4];
    const float* bp     = (const float*)d_in[5];
    float* out = (float*)d_out;
    // 512-thr blocks (8 waves share one 32KB sW) x fused body (<=64 regs total)
    // -> 4 blocks/CU by LDS, 8 waves/SIMD by regs = 32 waves/CU. 1024 blocks
    // = 4/CU exactly resident; 4 tiles/wave.
    interp1d_kernel<<<dim3(1024), dim3(512), 0, stream>>>(y, x, W, b, logdet, bp, out);
}